// Round 1
// 167.950 us; speedup vs baseline: 1.3711x; 1.3711x over previous
//
#include <hip/hip_runtime.h>
#include <hip/hip_bf16.h>

typedef unsigned short u16;
typedef unsigned int   u32;
typedef __attribute__((ext_vector_type(8))) short bf16x8;
typedef __attribute__((ext_vector_type(4))) float f32x4;

#define DEVI static __device__ __forceinline__

// ---------- helpers ----------
DEVI u16 f2bf(float f){
  u32 u = __float_as_uint(f);
  u = (u + 0x7fffu + ((u >> 16) & 1u)) >> 16;  // RNE
  return (u16)u;
}
DEVI float bf2f(u16 h){ return __uint_as_float(((u32)h) << 16); }

// HW packed f32->bf16 (RNE, matches f2bf bit-exactly on finite values)
DEVI u32 pk2(float a, float b){
  u32 r;
  asm("v_cvt_pk_bf16_f32 %0, %1, %2" : "=v"(r) : "v"(a), "v"(b));
  return r;
}
DEVI u16 cvt1(float f){ return (u16)pk2(f, f); }

// element index into a [rows][64] bf16 LDS tile, XOR-swizzled (G4)
DEVI int swz(int row, int col){ return row*64 + (col ^ ((row & 7) << 3)); }

// sync stage (used by the GEMM cores)
DEVI void stage64(u16* __restrict__ lds, const u16* __restrict__ g, int ld){
  int tid = threadIdx.x;
  #pragma unroll
  for (int c = tid; c < 512; c += 256){
    int row = c >> 3;
    int col = (c & 7) << 3;
    int4 v = *(const int4*)(g + (size_t)row*ld + col);
    *(int4*)(lds + swz(row, col)) = v;
  }
}

// async global->LDS, 16B per lane. LDS fill is linear (base + lane*16B);
// the swizzle is applied to the per-lane GLOBAL source address so the data
// lands exactly where swz() reads expect (both-sides-or-neither, G21).
DEVI void gload16(const u16* g, u16* l){
  typedef __attribute__((address_space(1))) u16 gu16;
  typedef __attribute__((address_space(3))) u16 lu16;
  __builtin_amdgcn_global_load_lds((gu16*)g, (lu16*)l, 16, 0, 0);
}

// stage a 64x64 bf16 tile (leading dim ld) into swizzled LDS, async
DEVI void stage64a(u16* lds, const u16* g, int ld){
  int w = threadIdx.x >> 6, l = threadIdx.x & 63;
  #pragma unroll
  for (int i = 0; i < 2; ++i){
    int e = (w*2 + i)*512 + l*8;
    int row = e >> 6, col = e & 63;
    gload16(g + (size_t)row*ld + (col ^ ((row & 7) << 3)), lds + (w*2 + i)*512);
  }
}

// stage the 128-row ErT window for tile-diff diff0, async
DEVI void stageEWa(u16* lds, const u16* Eg, int diff0){
  int w = threadIdx.x >> 6, l = threadIdx.x & 63;
  #pragma unroll
  for (int i = 0; i < 4; ++i){
    int e = (w*4 + i)*512 + l*8;
    int row = e >> 6, col = e & 63;
    bool useA = (diff0 < 0) | ((diff0 == 0) & (row < 64));
    int j = row + diff0 + (useA ? 1984 : -65);
    j = j < 0 ? 0 : (j > 2047 ? 2047 : j);
    gload16(Eg + (size_t)j*64 + (col ^ ((row & 7) << 3)), lds + (w*4 + i)*512);
  }
}

DEVI bf16x8 ldsfrag(const u16* lds, int row, int k){
  union { int4 i; bf16x8 b; } u;
  u.i = *(const int4*)(lds + swz(row, k));
  return u.b;
}

DEVI float rmax16(float v){
  #pragma unroll
  for (int m = 1; m < 16; m <<= 1) v = fmaxf(v, __shfl_xor(v, m, 16));
  return v;
}
DEVI float rsum16(float v){
  #pragma unroll
  for (int m = 1; m < 16; m <<= 1) v += __shfl_xor(v, m, 16);
  return v;
}

// ---------- pack kernels ----------
__global__ void k_castX(const float4* __restrict__ X, ushort4* __restrict__ Xb, int n4){
  int i = blockIdx.x*256 + threadIdx.x;
  if (i >= n4) return;
  float4 v = X[i];
  ushort4 o; o.x = f2bf(v.x); o.y = f2bf(v.y); o.z = f2bf(v.z); o.w = f2bf(v.w);
  Xb[i] = o;
}

// Wt[n][m], n = sel*512 + h*64 + d, value = W_sel[h][m][d]
__global__ void k_packW(const float* __restrict__ Wq, const float* __restrict__ Wk,
                        const float* __restrict__ Wv, u16* __restrict__ Wt){
  int i = blockIdx.x*256 + threadIdx.x;
  if (i >= 1536*512) return;
  int n = i >> 9, m = i & 511;
  int sel = n >> 9, hd = n & 511;
  int h = hd >> 6, d = hd & 63;
  const float* W = (sel == 0) ? Wq : ((sel == 1) ? Wk : Wv);
  Wt[i] = f2bf(W[((size_t)h*512 + m)*64 + d]);
}

__global__ void k_packWo(const float* __restrict__ Wo, u16* __restrict__ Wot){
  int i = blockIdx.x*256 + threadIdx.x;
  if (i >= 512*512) return;
  int n = i >> 9, m = i & 511;
  Wot[i] = f2bf(Wo[(size_t)m*512 + n]);
}

// ErT[h][t][d] = Er[h][d][t]   (REL_CLIP == S so slice offset is 0)
__global__ void k_packEr(const float* __restrict__ Er, u16* __restrict__ ErT){
  int i = blockIdx.x*256 + threadIdx.x;
  if (i >= 8*2048*64) return;
  int h = i >> 17, r = i & 131071;
  int t = r >> 6, d = r & 63;
  ErT[i] = f2bf(Er[((size_t)h*64 + d)*2048 + t]);
}

// ---------- generic 64x64-tile bf16 GEMM core (C = A * Bt^T over K) ----------
DEVI void gemm_core(const u16* __restrict__ Ag, int lda,
                    const u16* __restrict__ Bg, int ldb, int K,
                    u16* Alds, u16* Blds, f32x4 acc[4])
{
  int w = threadIdx.x >> 6, l = threadIdx.x & 63;
  int arow = w*16 + (l & 15);
  int kof  = (l >> 4) * 8;
  for (int k0 = 0; k0 < K; k0 += 64){
    __syncthreads();
    stage64(Alds, Ag + k0, lda);
    stage64(Blds, Bg + k0, ldb);
    __syncthreads();
    #pragma unroll
    for (int ks = 0; ks < 2; ++ks){
      bf16x8 a = ldsfrag(Alds, arow, ks*32 + kof);
      #pragma unroll
      for (int ct = 0; ct < 4; ++ct){
        bf16x8 b = ldsfrag(Blds, ct*16 + (l & 15), ks*32 + kof);
        acc[ct] = __builtin_amdgcn_mfma_f32_16x16x32_bf16(a, b, acc[ct], 0, 0, 0);
      }
    }
  }
}

// QKV: X(4096x512) @ Wt(1536x512)^T ; epilogue scatters Q(scaled)/K/V
__global__ __launch_bounds__(256) void k_gemm_qkv(
  const u16* __restrict__ X, const u16* __restrict__ Wt,
  u16* __restrict__ Q, u16* __restrict__ Ko, u16* __restrict__ Vn)
{
  __shared__ u16 Alds[64*64], Blds[64*64];
  int m0 = blockIdx.y * 64, n0 = blockIdx.x * 64;
  f32x4 acc[4];
  #pragma unroll
  for (int i = 0; i < 4; ++i) acc[i] = (f32x4){0.f,0.f,0.f,0.f};
  gemm_core(X + (size_t)m0*512, 512, Wt + (size_t)n0*512, 512, 512, Alds, Blds, acc);

  int w = threadIdx.x >> 6, l = threadIdx.x & 63;
  int rbase = m0 + w*16 + ((l >> 4) << 2);
  #pragma unroll
  for (int ct = 0; ct < 4; ++ct){
    int col = n0 + ct*16 + (l & 15);
    int sel = col >> 9;
    int hd  = col & 511;
    int h = hd >> 6, d = hd & 63;
    #pragma unroll
    for (int r = 0; r < 4; ++r){
      int row = rbase + r;
      int b = row >> 11, s = row & 2047;
      float v = acc[ct][r];
      if (sel == 0)      Q [(((size_t)(h*2 + b))*2048 + s)*64 + d] = f2bf(v * 0.125f);
      else if (sel == 1) Ko[(((size_t)(h*2 + b))*2048 + s)*64 + d] = f2bf(v);
      else               Vn[((size_t)row)*512 + hd] = f2bf(v);
    }
  }
}

// Vt[h][b][d][s]  <-  Vn[(b*2048+s)*512 + h*64 + d]
__global__ __launch_bounds__(256) void k_transV(const u16* __restrict__ Vn, u16* __restrict__ Vt){
  __shared__ u16 t[64][72];
  int hb = blockIdx.y, h = hb >> 1, b = hb & 1;
  int s0 = blockIdx.x * 64;
  int tid = threadIdx.x;
  for (int c = tid; c < 512; c += 256){
    int sr = c >> 3, col = (c & 7) << 3;
    int4 v = *(const int4*)(Vn + ((size_t)(b*2048 + s0 + sr))*512 + h*64 + col);
    *(int4*)(&t[sr][col]) = v;
  }
  __syncthreads();
  for (int c = tid; c < 512; c += 256){
    int dr = c >> 3, col = (c & 7) << 3;
    union { u16 e[8]; int4 v; } tmp;
    #pragma unroll
    for (int j = 0; j < 8; ++j) tmp.e[j] = t[col + j][dr];
    *(int4*)(Vt + ((size_t)(hb*64 + dr))*2048 + s0 + col) = tmp.v;
  }
}

// flash attention; Srel computed in-kernel from ErT window via MFMA.
// Pipelined: K/V double-buffered via async global_load_lds prefetched one
// iteration ahead; EW prefetched mid-iteration behind a raw s_barrier.
// Rs is a per-warp compact [80 cols][16 rows] diagonal-band store.
__global__ __launch_bounds__(256) void k_attn(
  const u16* __restrict__ Q, const u16* __restrict__ Kg_, const u16* __restrict__ Vt,
  const u16* __restrict__ ErT, const float* __restrict__ mask, u16* __restrict__ AO)
{
  __shared__ u16 QsPs[66*64];      // Q rows p0..p0+64 in prologue; P tile afterwards
  __shared__ u16 Ks[2*64*64];      // double-buffered K tile
  __shared__ u16 Vs[2*64*64];      // double-buffered V tile
  __shared__ u16 EW[128*64];       // ErT window (single buffer)
  __shared__ u16 Rs[4*80*16];      // per-warp compact R band

  int tid = threadIdx.x;
  int w = tid >> 6, l = tid & 63;
  int hb = blockIdx.y, h = hb >> 1, b = hb & 1;
  int p0 = blockIdx.x * 64;
  const u16* Qg  = Q   + (size_t)hb*2048*64;
  const u16* Kgg = Kg_ + (size_t)hb*2048*64;
  const u16* Vg  = Vt  + (size_t)hb*64*2048;
  const u16* Eg  = ErT + (size_t)h*2048*64;

  // prologue: issue async stages for tile 0
  stage64a(Ks, Kgg, 64);
  stage64a(Vs, Vg, 2048);
  stageEWa(EW, Eg, -p0);

  // stage 65 Q rows (p0 .. p0+64, clamped; row 64 feeds the qb "p+1" fragments)
  for (int c = tid; c < 520; c += 256){
    int row = c >> 3, col = (c & 7) << 3;
    int gr = p0 + row; if (gr > 2047) gr = 2047;
    *(int4*)(QsPs + swz(row, col)) = *(const int4*)(Qg + (size_t)gr*64 + col);
  }
  __syncthreads();   // drains vmcnt: Q staged + K0/V0/EW0 landed

  int kof = (l >> 4) * 8;
  int l15 = l & 15;
  int arow = w*16 + l15;
  int ribase = (l >> 4) * 4;
  bf16x8 qa0 = ldsfrag(QsPs, arow,     kof);
  bf16x8 qa1 = ldsfrag(QsPs, arow,     32 + kof);
  bf16x8 qb0 = ldsfrag(QsPs, arow + 1, kof);
  bf16x8 qb1 = ldsfrag(QsPs, arow + 1, 32 + kof);

  float mrun[4], lrun[4];
  f32x4 o[4];
  #pragma unroll
  for (int r = 0; r < 4; ++r){ mrun[r] = -1e30f; lrun[r] = 0.f; }
  #pragma unroll
  for (int dt = 0; dt < 4; ++dt) o[dt] = (f32x4){0.f,0.f,0.f,0.f};

  u16* Rw = Rs + w*1280;   // this warp's [80][16] band
  int p = 0;

  for (int t0 = 0; t0 < 2048; t0 += 64){
    int diff0 = t0 - p0;
    const u16* Ksp = Ks + p*4096;
    const u16* Vsp = Vs + p*4096;

    // mask loads FIRST (so their waitcnt never drains the prefetches below)
    float mk[4][4];
    #pragma unroll
    for (int ct = 0; ct < 4; ++ct){
      #pragma unroll
      for (int r = 0; r < 4; ++r)
        mk[ct][r] = mask[(size_t)(p0 + w*16 + ribase + r)*2048 + t0 + ct*16 + l15];
    }

    // prefetch next K/V tiles into the alternate buffers (in flight across
    // the whole compute phase; drained by the end-of-iter __syncthreads)
    if (t0 < 1984){
      stage64a(Ks + (p^1)*4096, Kgg + (size_t)(t0 + 64)*64, 64);
      stage64a(Vs + (p^1)*4096, Vg + (t0 + 64), 2048);
    }

    // QK^T
    float sv[4][4];
    #pragma unroll
    for (int ct = 0; ct < 4; ++ct){
      f32x4 s = (f32x4){0.f,0.f,0.f,0.f};
      s = __builtin_amdgcn_mfma_f32_16x16x32_bf16(qa0, ldsfrag(Ksp, ct*16 + l15, kof),      s, 0, 0, 0);
      s = __builtin_amdgcn_mfma_f32_16x16x32_bf16(qa1, ldsfrag(Ksp, ct*16 + l15, 32 + kof), s, 0, 0, 0);
      #pragma unroll
      for (int r = 0; r < 4; ++r) sv[ct][r] = s[r];
    }

    // R = Qtile @ EW^T — only the 5 column-tiles this warp's band needs.
    // Warp w gathers cols [48-16w, 126-16w] => tiles ct2 in [3-w, 7-w].
    // A-rows (pi) and B-rows (pi+1) land at the same local row index and
    // disjoint column tiles, so one compact plane suffices.
    {
      bool allB = diff0 > 0, diag = diff0 == 0;
      #pragma unroll
      for (int j5 = 0; j5 < 5; ++j5){
        int ct2 = (3 - w) + j5;
        bool useB = allB | (diag & (ct2 >= 4));
        f32x4 rr = (f32x4){0.f,0.f,0.f,0.f};
        rr = __builtin_amdgcn_mfma_f32_16x16x32_bf16(useB ? qb0 : qa0, ldsfrag(EW, ct2*16 + l15, kof),      rr, 0, 0, 0);
        rr = __builtin_amdgcn_mfma_f32_16x16x32_bf16(useB ? qb1 : qa1, ldsfrag(EW, ct2*16 + l15, 32 + kof), rr, 0, 0, 0);
        uint2 pv;
        pv.x = pk2(rr[0], rr[1]);
        pv.y = pk2(rr[2], rr[3]);
        *(uint2*)(Rw + (j5*16 + l15)*16 + ribase) = pv;   // 8B-aligned ds_write_b64
      }
    }

    // all warps are done reading EW (their EW ds_reads were consumed by the
    // MFMAs above); raw barrier does NOT drain the K/V prefetch vmcnt
    __builtin_amdgcn_s_barrier();
    if (t0 < 1984) stageEWa(EW, Eg, diff0 + 64);   // hidden under softmax+PV

    // gather Srel (single branchless read from own-warp band) + softmax
    #pragma unroll
    for (int ct = 0; ct < 4; ++ct){
      int ti = ct*16 + l15;
      #pragma unroll
      for (int r = 0; r < 4; ++r){
        int pl = ribase + r;
        int rg = diff0 + ti - (w*16 + pl);
        float srl = bf2f(Rw[(15 + ti - pl)*16 + pl]);
        srl = (rg == 1) ? 0.f : srl;
        sv[ct][r] += mk[ct][r] + srl;
      }
    }

    #pragma unroll
    for (int r = 0; r < 4; ++r){
      float tm = fmaxf(fmaxf(sv[0][r], sv[1][r]), fmaxf(sv[2][r], sv[3][r]));
      tm = rmax16(tm);
      float mn = fmaxf(mrun[r], tm);
      float corr = __expf(mrun[r] - mn);
      mrun[r] = mn;
      lrun[r] *= corr;
      #pragma unroll
      for (int dt = 0; dt < 4; ++dt) o[dt][r] *= corr;
      float ps = 0.f;
      #pragma unroll
      for (int ct = 0; ct < 4; ++ct){
        float pv = __expf(sv[ct][r] - mn);
        ps += pv;
        QsPs[swz(w*16 + ribase + r, ct*16 + l15)] = cvt1(pv);
      }
      lrun[r] += rsum16(ps);
    }

    #pragma unroll
    for (int ks = 0; ks < 2; ++ks){
      bf16x8 pa = ldsfrag(QsPs, arow, ks*32 + kof);
      #pragma unroll
      for (int dt = 0; dt < 4; ++dt){
        bf16x8 vb = ldsfrag(Vsp, dt*16 + l15, ks*32 + kof);
        o[dt] = __builtin_amdgcn_mfma_f32_16x16x32_bf16(pa, vb, o[dt], 0, 0, 0);
      }
    }

    __syncthreads();   // drains prefetches; syncs readers before next iter
    p ^= 1;
  }

  #pragma unroll
  for (int r = 0; r < 4; ++r){
    float inv = 1.0f / lrun[r];
    int pp = p0 + w*16 + ribase + r;
    #pragma unroll
    for (int dt = 0; dt < 4; ++dt)
      AO[((size_t)(b*2048 + pp))*512 + h*64 + dt*16 + l15] = cvt1(o[dt][r] * inv);
  }
}

// out(4096x512 f32) = AO(4096x512 bf16) @ Wot(512x512)^T
__global__ __launch_bounds__(256) void k_gemm_wo(
  const u16* __restrict__ AO, const u16* __restrict__ Wot, float* __restrict__ out)
{
  __shared__ u16 Alds[64*64], Blds[64*64];
  int m0 = blockIdx.y * 64, n0 = blockIdx.x * 64;
  f32x4 acc[4];
  #pragma unroll
  for (int i = 0; i < 4; ++i) acc[i] = (f32x4){0.f,0.f,0.f,0.f};
  gemm_core(AO + (size_t)m0*512, 512, Wot + (size_t)n0*512, 512, 512, Alds, Blds, acc);

  int w = threadIdx.x >> 6, l = threadIdx.x & 63;
  int rbase = m0 + w*16 + ((l >> 4) << 2);
  #pragma unroll
  for (int ct = 0; ct < 4; ++ct){
    int col = n0 + ct*16 + (l & 15);
    #pragma unroll
    for (int r = 0; r < 4; ++r)
      out[(size_t)(rbase + r)*512 + col] = acc[ct][r];
  }
}

// ---------- launch ----------
extern "C" void kernel_launch(void* const* d_in, const int* in_sizes, int n_in,
                              void* d_out, int out_size, void* d_ws, size_t ws_size,
                              hipStream_t stream)
{
  const float* X    = (const float*)d_in[0];
  const float* mask = (const float*)d_in[1];
  const float* Wq   = (const float*)d_in[2];
  const float* Wk   = (const float*)d_in[3];
  const float* Wv   = (const float*)d_in[4];
  const float* Wo   = (const float*)d_in[5];
  const float* Er   = (const float*)d_in[6];
  float* out = (float*)d_out;

  char* p = (char*)d_ws;
  auto carve = [&](size_t bytes)->char*{ char* r = p; p += (bytes + 255) & ~(size_t)255; return r; };
  u16* Xbf = (u16*)carve(4096ull*512*2);     // 4 MB
  u16* Wt  = (u16*)carve(1536ull*512*2);     // 1.5 MB
  u16* Wot = (u16*)carve(512ull*512*2);      // 0.5 MB
  u16* ErT = (u16*)carve(8ull*2048*64*2);    // 2 MB
  u16* Qb  = (u16*)carve(16ull*2048*64*2);   // 4 MB (h,b,s,d) scaled
  u16* Kb  = (u16*)carve(16ull*2048*64*2);   // 4 MB (h,b,s,d)
  u16* Vn  = (u16*)carve(4096ull*512*2);     // 4 MB (b,s,h*64+d)
  u16* Vt  = (u16*)carve(16ull*64*2048*2);   // 4 MB (h,b,d,s)
  u16* AO  = (u16*)carve(4096ull*512*2);     // 4 MB (b,s,h*64+d)

  k_castX  <<<dim3(2048), dim3(256), 0, stream>>>((const float4*)X, (ushort4*)Xbf, 524288);
  k_packW  <<<dim3(3072), dim3(256), 0, stream>>>(Wq, Wk, Wv, Wt);
  k_packWo <<<dim3(1024), dim3(256), 0, stream>>>(Wo, Wot);
  k_packEr <<<dim3(4096), dim3(256), 0, stream>>>(Er, ErT);

  k_gemm_qkv<<<dim3(24, 64), dim3(256), 0, stream>>>(Xbf, Wt, Qb, Kb, Vn);
  k_transV  <<<dim3(32, 16), dim3(256), 0, stream>>>(Vn, Vt);
  k_attn    <<<dim3(32, 16), dim3(256), 0, stream>>>(Qb, Kb, Vt, ErT, mask, AO);
  k_gemm_wo <<<dim3(8, 64), dim3(256), 0, stream>>>(AO, Wot, out);

  (void)in_sizes; (void)n_in; (void)out_size; (void)ws_size;
}